// Round 1
// baseline (158.390 us; speedup 1.0000x reference)
//
#include <hip/hip_runtime.h>
#include <hip/hip_bf16.h>

typedef __attribute__((ext_vector_type(4))) float f32x4;
typedef __attribute__((ext_vector_type(8))) short s16x8;

__device__ __forceinline__ short f2bf(float f) {
  union { float f; unsigned u; } v; v.f = f;
  unsigned r = v.u + 0x7fffu + ((v.u >> 16) & 1u);
  return (short)(r >> 16);
}

// K0: NCHW x (2,32,192,192) -> zero-padded NHWC xp (2,194,194,32)
__global__ __launch_bounds__(256) void k_pad_nhwc(const float* __restrict__ x,
                                                  float* __restrict__ xp) {
  int t = blockIdx.x * 256 + threadIdx.x;
  if (t >= 2 * 194 * 194) return;
  int b = t / (194 * 194);
  int r = t % (194 * 194);
  int qx = r / 194, qy = r % 194;
  float* dst = xp + (size_t)t * 32;
  int i = qx - 1, j = qy - 1;
  bool ok = ((unsigned)i < 192u) && ((unsigned)j < 192u);
  const float* src = x + (size_t)b * 32 * 192 * 192 + i * 192 + j;
  #pragma unroll
  for (int c = 0; c < 32; c++) dst[c] = ok ? src[c * 36864] : 0.f;
}

// K1: A = conv3x3(x, p1_w, pad=1) + p1_b   -> (2,192,192)
__global__ __launch_bounds__(256) void k_amap(const float* __restrict__ xp,
                                              const float* __restrict__ p1w,
                                              const float* __restrict__ p1b,
                                              float* __restrict__ Amap) {
  int t = blockIdx.x * 256 + threadIdx.x;
  if (t >= 2 * 192 * 192) return;
  int b = t / 36864;
  int r = t % 36864;
  int i = r / 192, j = r % 192;
  float a = p1b[0];
  const float* base = xp + ((size_t)b * 194 * 194 + i * 194 + j) * 32;
  #pragma unroll
  for (int kh = 0; kh < 3; kh++)
    #pragma unroll
    for (int kw = 0; kw < 3; kw++) {
      const float* q = base + (kh * 194 + kw) * 32;
      const float* w = p1w + kh * 3 + kw;
      #pragma unroll
      for (int c = 0; c < 32; c++)
        a = fmaf(q[c], w[c * 9], a);
    }
  Amap[t] = a;
}

// K2: conv_w (64,32,3,3) -> bf16 B-fragments wf[n][otile][lane][8]
//     B[k = quad*8+j][o = otile*16 + (lane&15)], k-slice n covers channels.
__global__ __launch_bounds__(256) void k_wfrag(const float* __restrict__ w,
                                               short* __restrict__ wf) {
  int t = blockIdx.x * 256 + threadIdx.x;
  if (t >= 9 * 4 * 64) return;
  int n = t / 256;
  int ot = (t / 64) % 4;
  int lane = t % 64;
  int o = ot * 16 + (lane & 15);
  int cb = (lane >> 4) * 8;
  #pragma unroll
  for (int jj = 0; jj < 8; jj++) {
    float v = w[(o * 32 + cb + jj) * 9 + n];
    wf[(size_t)t * 8 + jj] = f2bf(v);
  }
}

// K3: per wave: 16 pixels of one row; 9 n-steps of bilinear sampling (K=32
// channels each) -> bf16 A-frag -> 4 MFMAs (o-tiles of 16). fp32 out.
__global__ __launch_bounds__(256) void k_main(const float* __restrict__ xp,
                                              const float* __restrict__ Amap,
                                              const s16x8* __restrict__ wfv,
                                              float* __restrict__ out) {
  int lane = threadIdx.x & 63;
  int W = blockIdx.x * 4 + (threadIdx.x >> 6);
  int b = W / 2304;
  int r = W % 2304;
  int i = r / 12;
  int j0 = (r % 12) * 16;
  int m = lane & 15, quad = lane >> 4, cb = quad * 8;
  int j = j0 + m;
  float A = Amap[b * 36864 + i * 192 + j];
  const float* xpb = xp + (size_t)b * (194 * 194 * 32);
  f32x4 acc0 = {0.f, 0.f, 0.f, 0.f};
  f32x4 acc1 = acc0, acc2 = acc0, acc3 = acc0;
  float cx = (float)(i + 1), cy = (float)(j + 1);
  #pragma unroll
  for (int n = 0; n < 9; n++) {
    float px = cx + A * (float)(n / 3 - 1);
    float py = cy + A * (float)(n % 3 - 1);
    float flx = floorf(px), fly = floorf(py);
    float qltx = fminf(fmaxf(flx, 0.f), 193.f);
    float qlty = fminf(fmaxf(fly, 0.f), 193.f);
    float qrbx = fminf(fmaxf(flx + 1.f, 0.f), 193.f);
    float qrby = fminf(fmaxf(fly + 1.f, 0.f), 193.f);
    float pxc = fminf(fmaxf(px, 0.f), 193.f);
    float pyc = fminf(fmaxf(py, 0.f), 193.f);
    float gxl = 1.f + (qltx - pxc);
    float gxr = 1.f - (qrbx - pxc);
    float gyl = 1.f + (qlty - pyc);
    float gyr = 1.f - (qrby - pyc);
    float g_lt = gxl * gyl, g_rb = gxr * gyr, g_lb = gxl * gyr, g_rt = gxr * gyl;
    int ixl = (int)qltx, iyl = (int)qlty, ixr = (int)qrbx, iyr = (int)qrby;
    const float* plt = xpb + (ixl * 194 + iyl) * 32 + cb;
    const float* prb = xpb + (ixr * 194 + iyr) * 32 + cb;
    const float* plb = xpb + (ixl * 194 + iyr) * 32 + cb;
    const float* prt = xpb + (ixr * 194 + iyl) * 32 + cb;
    f32x4 lt0 = *(const f32x4*)plt, lt1 = *(const f32x4*)(plt + 4);
    f32x4 rb0 = *(const f32x4*)prb, rb1 = *(const f32x4*)(prb + 4);
    f32x4 lb0 = *(const f32x4*)plb, lb1 = *(const f32x4*)(plb + 4);
    f32x4 rt0 = *(const f32x4*)prt, rt1 = *(const f32x4*)(prt + 4);
    f32x4 s0 = g_lt * lt0 + g_rb * rb0 + g_lb * lb0 + g_rt * rt0;
    f32x4 s1 = g_lt * lt1 + g_rb * rb1 + g_lb * lb1 + g_rt * rt1;
    s16x8 af;
    af[0] = f2bf(s0[0]); af[1] = f2bf(s0[1]); af[2] = f2bf(s0[2]); af[3] = f2bf(s0[3]);
    af[4] = f2bf(s1[0]); af[5] = f2bf(s1[1]); af[6] = f2bf(s1[2]); af[7] = f2bf(s1[3]);
    int wb = n * 256 + lane;
    acc0 = __builtin_amdgcn_mfma_f32_16x16x32_bf16(af, wfv[wb], acc0, 0, 0, 0);
    acc1 = __builtin_amdgcn_mfma_f32_16x16x32_bf16(af, wfv[wb + 64], acc1, 0, 0, 0);
    acc2 = __builtin_amdgcn_mfma_f32_16x16x32_bf16(af, wfv[wb + 128], acc2, 0, 0, 0);
    acc3 = __builtin_amdgcn_mfma_f32_16x16x32_bf16(af, wfv[wb + 192], acc3, 0, 0, 0);
  }
  // D layout: row(pixel) = quad*4 + reg, col(o) = lane&15
  int o0 = lane & 15;
  int jout = j0 + quad * 4;
  float* op = out + (size_t)b * 64 * 36864 + (size_t)o0 * 36864 + i * 192 + jout;
  *(f32x4*)(op) = acc0;
  *(f32x4*)(op + 16 * 36864) = acc1;
  *(f32x4*)(op + 32 * 36864) = acc2;
  *(f32x4*)(op + 48 * 36864) = acc3;
}

extern "C" void kernel_launch(void* const* d_in, const int* in_sizes, int n_in,
                              void* d_out, int out_size, void* d_ws, size_t ws_size,
                              hipStream_t stream) {
  const float* x      = (const float*)d_in[0];
  const float* conv_w = (const float*)d_in[1];
  // d_in[2]=p_conv_w (zeros, dead), d_in[3]=p_conv_b (dead in the math)
  const float* p1w    = (const float*)d_in[4];
  const float* p1b    = (const float*)d_in[5];
  float* out = (float*)d_out;

  float* xp   = (float*)d_ws;                   // 2*194*194*32 = 2,408,704 f
  float* Amap = xp + 2 * 194 * 194 * 32;        // 73,728 f
  short* wf   = (short*)(Amap + 2 * 192 * 192); // 9*4*64*8 bf16

  k_pad_nhwc<<<(2 * 194 * 194 + 255) / 256, 256, 0, stream>>>(x, xp);
  k_amap<<<(2 * 192 * 192 + 255) / 256, 256, 0, stream>>>(xp, p1w, p1b, Amap);
  k_wfrag<<<9, 256, 0, stream>>>(conv_w, wf);
  k_main<<<1152, 256, 0, stream>>>(xp, Amap, (const s16x8*)wf, out);
}

// Round 2
// 136.014 us; speedup vs baseline: 1.1645x; 1.1645x over previous
//
#include <hip/hip_runtime.h>
#include <hip/hip_bf16.h>

typedef __attribute__((ext_vector_type(4))) float f32x4;
typedef __attribute__((ext_vector_type(8))) short s16x8;

__device__ __forceinline__ short f2bf(float f) {
  union { float f; unsigned u; } v; v.f = f;
  unsigned r = v.u + 0x7fffu + ((v.u >> 16) & 1u);
  return (short)(r >> 16);
}

// K0: NCHW x (2,32,192,192) -> zero-padded NHWC xp (2,194,194,32)
// thread = (pixel, c4-group of 4 channels); writes fully coalesced float4.
__global__ __launch_bounds__(256) void k_pad_nhwc(const float* __restrict__ x,
                                                  float* __restrict__ xp) {
  int t = blockIdx.x * 256 + threadIdx.x;
  if (t >= 2 * 194 * 194 * 8) return;
  int pix = t >> 3, c4 = t & 7;
  int b = pix / (194 * 194);
  int r = pix % (194 * 194);
  int qx = r / 194, qy = r % 194;
  int i = qx - 1, j = qy - 1;
  bool ok = ((unsigned)i < 192u) && ((unsigned)j < 192u);
  const float* src = x + (size_t)b * 32 * 36864 + (size_t)(c4 * 4) * 36864 + i * 192 + j;
  f32x4 v;
  v[0] = ok ? src[0]         : 0.f;
  v[1] = ok ? src[36864]     : 0.f;
  v[2] = ok ? src[2 * 36864] : 0.f;
  v[3] = ok ? src[3 * 36864] : 0.f;
  *(f32x4*)(xp + (size_t)pix * 32 + c4 * 4) = v;
}

// K1: A = conv3x3(x, p1_w, pad=1) + p1_b -> (2,192,192)
// thread = (pixel, quad of 8 channels); weights in LDS; shfl reduce over 4 lanes.
__global__ __launch_bounds__(256) void k_amap(const float* __restrict__ xp,
                                              const float* __restrict__ p1w,
                                              const float* __restrict__ p1b,
                                              float* __restrict__ Amap) {
  __shared__ float wlds[288];
  for (int idx = threadIdx.x; idx < 288; idx += 256) wlds[idx] = p1w[idx];
  __syncthreads();
  int t = blockIdx.x * 256 + threadIdx.x;
  if (t >= 2 * 192 * 192 * 4) return;
  int pix = t >> 2, q = t & 3;
  int b = pix / 36864;
  int r = pix % 36864;
  int i = r / 192, j = r % 192;
  const float* base = xp + ((size_t)b * 194 * 194 + i * 194 + j) * 32 + q * 8;
  float a = 0.f;
  #pragma unroll
  for (int tap = 0; tap < 9; tap++) {
    int kh = tap / 3, kw = tap % 3;
    const float* p = base + (kh * 194 + kw) * 32;
    f32x4 v0 = *(const f32x4*)p;
    f32x4 v1 = *(const f32x4*)(p + 4);
    #pragma unroll
    for (int k = 0; k < 4; k++) {
      a = fmaf(v0[k], wlds[(q * 8 + k) * 9 + tap], a);
      a = fmaf(v1[k], wlds[(q * 8 + 4 + k) * 9 + tap], a);
    }
  }
  a += __shfl_xor(a, 1);
  a += __shfl_xor(a, 2);
  if (q == 0) Amap[pix] = a + p1b[0];
}

// K2: conv_w (64,32,3,3) -> bf16 B-fragments wf[n][otile][lane][8]
__global__ __launch_bounds__(256) void k_wfrag(const float* __restrict__ w,
                                               short* __restrict__ wf) {
  int t = blockIdx.x * 256 + threadIdx.x;
  if (t >= 9 * 4 * 64) return;
  int n = t / 256;
  int ot = (t / 64) % 4;
  int lane = t % 64;
  int o = ot * 16 + (lane & 15);
  int cb = (lane >> 4) * 8;
  #pragma unroll
  for (int jj = 0; jj < 8; jj++) {
    float v = w[(o * 32 + cb + jj) * 9 + n];
    wf[(size_t)t * 8 + jj] = f2bf(v);
  }
}

__device__ __forceinline__ void step_calc(int n, float A, float cx, float cy, int cb,
                                          int* off, float* g) {
  float px = cx + A * (float)(n / 3 - 1);
  float py = cy + A * (float)(n % 3 - 1);
  float flx = floorf(px), fly = floorf(py);
  float qltx = fminf(fmaxf(flx, 0.f), 193.f);
  float qlty = fminf(fmaxf(fly, 0.f), 193.f);
  float qrbx = fminf(fmaxf(flx + 1.f, 0.f), 193.f);
  float qrby = fminf(fmaxf(fly + 1.f, 0.f), 193.f);
  float pxc = fminf(fmaxf(px, 0.f), 193.f);
  float pyc = fminf(fmaxf(py, 0.f), 193.f);
  float gxl = 1.f + (qltx - pxc);
  float gxr = 1.f - (qrbx - pxc);
  float gyl = 1.f + (qlty - pyc);
  float gyr = 1.f - (qrby - pyc);
  g[0] = gxl * gyl; g[1] = gxr * gyr; g[2] = gxl * gyr; g[3] = gxr * gyl;
  int ixl = (int)qltx, iyl = (int)qlty, ixr = (int)qrbx, iyr = (int)qrby;
  off[0] = (ixl * 194 + iyl) * 32 + cb;
  off[1] = (ixr * 194 + iyr) * 32 + cb;
  off[2] = (ixl * 194 + iyr) * 32 + cb;
  off[3] = (ixr * 194 + iyl) * 32 + cb;
}

// K3: one wave per 16-pixel row segment; depth-1 pipelined gathers + 4 MFMAs/step.
__global__ __launch_bounds__(256) void k_main(const float* __restrict__ xp,
                                              const float* __restrict__ Amap,
                                              const s16x8* __restrict__ wfv,
                                              float* __restrict__ out) {
  int lane = threadIdx.x & 63;
  // XCD swizzle: 1152 blocks = 8 XCDs x 144 contiguous row-segments each.
  int bs = (blockIdx.x & 7) * 144 + (blockIdx.x >> 3);
  int W = bs * 4 + (threadIdx.x >> 6);
  int b = W / 2304;
  int r = W % 2304;
  int i = r / 12;
  int j0 = (r % 12) * 16;
  int m = lane & 15, quad = lane >> 4, cb = quad * 8;
  int j = j0 + m;
  float A = Amap[b * 36864 + i * 192 + j];
  const float* xpb = xp + (size_t)b * (194 * 194 * 32);
  f32x4 acc0 = {0.f, 0.f, 0.f, 0.f};
  f32x4 acc1 = acc0, acc2 = acc0, acc3 = acc0;
  float cx = (float)(i + 1), cy = (float)(j + 1);

  int offA[4]; float gA[4]; f32x4 bufA[8];
  int offB[4]; float gB[4]; f32x4 bufB[8];
  step_calc(0, A, cx, cy, cb, offA, gA);
  #pragma unroll
  for (int c = 0; c < 4; c++) {
    bufA[2 * c]     = *(const f32x4*)(xpb + offA[c]);
    bufA[2 * c + 1] = *(const f32x4*)(xpb + offA[c] + 4);
  }
  #pragma unroll
  for (int n = 0; n < 9; n++) {
    if (n < 8) {
      step_calc(n + 1, A, cx, cy, cb, offB, gB);
      #pragma unroll
      for (int c = 0; c < 4; c++) {
        bufB[2 * c]     = *(const f32x4*)(xpb + offB[c]);
        bufB[2 * c + 1] = *(const f32x4*)(xpb + offB[c] + 4);
      }
    }
    f32x4 s0 = gA[0] * bufA[0] + gA[1] * bufA[2] + gA[2] * bufA[4] + gA[3] * bufA[6];
    f32x4 s1 = gA[0] * bufA[1] + gA[1] * bufA[3] + gA[2] * bufA[5] + gA[3] * bufA[7];
    s16x8 af;
    af[0] = f2bf(s0[0]); af[1] = f2bf(s0[1]); af[2] = f2bf(s0[2]); af[3] = f2bf(s0[3]);
    af[4] = f2bf(s1[0]); af[5] = f2bf(s1[1]); af[6] = f2bf(s1[2]); af[7] = f2bf(s1[3]);
    int wb = n * 256 + lane;
    acc0 = __builtin_amdgcn_mfma_f32_16x16x32_bf16(af, wfv[wb],       acc0, 0, 0, 0);
    acc1 = __builtin_amdgcn_mfma_f32_16x16x32_bf16(af, wfv[wb + 64],  acc1, 0, 0, 0);
    acc2 = __builtin_amdgcn_mfma_f32_16x16x32_bf16(af, wfv[wb + 128], acc2, 0, 0, 0);
    acc3 = __builtin_amdgcn_mfma_f32_16x16x32_bf16(af, wfv[wb + 192], acc3, 0, 0, 0);
    #pragma unroll
    for (int c = 0; c < 8; c++) bufA[c] = bufB[c];
    #pragma unroll
    for (int c = 0; c < 4; c++) gA[c] = gB[c];
  }
  // D layout: row(pixel) = quad*4 + reg, col(o) = lane&15
  int o0 = lane & 15;
  int jout = j0 + quad * 4;
  float* op = out + (size_t)b * 64 * 36864 + (size_t)o0 * 36864 + i * 192 + jout;
  *(f32x4*)(op) = acc0;
  *(f32x4*)(op + 16 * 36864) = acc1;
  *(f32x4*)(op + 32 * 36864) = acc2;
  *(f32x4*)(op + 48 * 36864) = acc3;
}

extern "C" void kernel_launch(void* const* d_in, const int* in_sizes, int n_in,
                              void* d_out, int out_size, void* d_ws, size_t ws_size,
                              hipStream_t stream) {
  const float* x      = (const float*)d_in[0];
  const float* conv_w = (const float*)d_in[1];
  const float* p1w    = (const float*)d_in[4];
  const float* p1b    = (const float*)d_in[5];
  float* out = (float*)d_out;

  float* xp   = (float*)d_ws;                   // 2*194*194*32 floats
  float* Amap = xp + 2 * 194 * 194 * 32;        // 73,728 floats
  short* wf   = (short*)(Amap + 2 * 192 * 192); // 9*4*64*8 bf16

  k_pad_nhwc<<<(2 * 194 * 194 * 8 + 255) / 256, 256, 0, stream>>>(x, xp);
  k_amap<<<(2 * 192 * 192 * 4 + 255) / 256, 256, 0, stream>>>(xp, p1w, p1b, Amap);
  k_wfrag<<<9, 256, 0, stream>>>(conv_w, wf);
  k_main<<<1152, 256, 0, stream>>>(xp, Amap, (const s16x8*)wf, out);
}

// Round 3
// 100.367 us; speedup vs baseline: 1.5781x; 1.3552x over previous
//
#include <hip/hip_runtime.h>

typedef __attribute__((ext_vector_type(4))) float f32x4;
typedef __attribute__((ext_vector_type(4))) int   i32x4;
typedef __attribute__((ext_vector_type(8))) short s16x8;

__device__ __forceinline__ unsigned short f2bf(float f) {
  union { float f; unsigned u; } v; v.f = f;
  unsigned r = v.u + 0x7fffu + ((v.u >> 16) & 1u);
  return (unsigned short)(r >> 16);
}

// unpack 8 bf16 (as i32x4) and accumulate g*x into s0(ch0..3), s1(ch4..7)
__device__ __forceinline__ void add8(i32x4 v, float g, f32x4& s0, f32x4& s1) {
  union { int ii; float ff; } u;
  u.ii = v[0] << 16;                  s0[0] = fmaf(g, u.ff, s0[0]);
  u.ii = v[0] & (int)0xffff0000u;     s0[1] = fmaf(g, u.ff, s0[1]);
  u.ii = v[1] << 16;                  s0[2] = fmaf(g, u.ff, s0[2]);
  u.ii = v[1] & (int)0xffff0000u;     s0[3] = fmaf(g, u.ff, s0[3]);
  u.ii = v[2] << 16;                  s1[0] = fmaf(g, u.ff, s1[0]);
  u.ii = v[2] & (int)0xffff0000u;     s1[1] = fmaf(g, u.ff, s1[1]);
  u.ii = v[3] << 16;                  s1[2] = fmaf(g, u.ff, s1[2]);
  u.ii = v[3] & (int)0xffff0000u;     s1[3] = fmaf(g, u.ff, s1[3]);
}

// K0: NCHW fp32 x (2,32,192,192) -> zero-padded bf16 NHWC xp (2,194,194,32)
// thread = (padded pixel, group of 8 channels); 16-B coalesced stores.
__global__ __launch_bounds__(256) void k_prep(const float* __restrict__ x,
                                              unsigned short* __restrict__ xp) {
  int t = blockIdx.x * 256 + threadIdx.x;
  if (t >= 2 * 194 * 194 * 4) return;
  int pix = t >> 2, c8 = t & 3;
  int b = pix / (194 * 194);
  int r = pix % (194 * 194);
  int i = r / 194 - 1, j = r % 194 - 1;
  bool ok = ((unsigned)i < 192u) && ((unsigned)j < 192u);
  const float* src = x + (size_t)b * 32 * 36864 + (size_t)(c8 * 8) * 36864 + i * 192 + j;
  unsigned v[8];
  #pragma unroll
  for (int k = 0; k < 8; k++) v[k] = ok ? (unsigned)f2bf(src[k * 36864]) : 0u;
  i32x4 pv;
  pv[0] = (int)(v[0] | (v[1] << 16));
  pv[1] = (int)(v[2] | (v[3] << 16));
  pv[2] = (int)(v[4] | (v[5] << 16));
  pv[3] = (int)(v[6] | (v[7] << 16));
  *(i32x4*)(xp + (size_t)pix * 32 + c8 * 8) = pv;
}

// K1: conv_w (64,32,3,3) fp32 -> bf16 MFMA B-fragments wf[n][otile][lane][8]
// B[k = quad*8+jj][o = otile*16 + (lane&15)], K-slice n covers channels.
__global__ __launch_bounds__(256) void k_wfrag(const float* __restrict__ w,
                                               short* __restrict__ wf) {
  int t = blockIdx.x * 256 + threadIdx.x;
  if (t >= 9 * 4 * 64) return;
  int n = t / 256;
  int ot = (t / 64) % 4;
  int lane = t % 64;
  int o = ot * 16 + (lane & 15);
  int cb = (lane >> 4) * 8;
  #pragma unroll
  for (int jj = 0; jj < 8; jj++) {
    float v = w[(o * 32 + cb + jj) * 9 + n];
    wf[(size_t)t * 8 + jj] = (short)f2bf(v);
  }
}

// K2: fused A-map + bilinear sampling + MFMA contraction.
// wave = 16 pixels of one row; lane = (pixel m, channel-quad); fp32 out.
__global__ __launch_bounds__(256) void k_main(const unsigned short* __restrict__ xp,
                                              const float* __restrict__ p1w,
                                              const float* __restrict__ p1b,
                                              const s16x8* __restrict__ wfv,
                                              float* __restrict__ out) {
  __shared__ float wlds[288];  // reordered p1w: wlds[tap*32 + c]
  for (int idx = threadIdx.x; idx < 288; idx += 256) {
    int c = idx / 9, tap = idx % 9;
    wlds[tap * 32 + c] = p1w[idx];
  }
  __syncthreads();

  int lane = threadIdx.x & 63;
  // XCD swizzle: 1152 blocks = 8 XCDs x 144 contiguous row-segments.
  int bs = (blockIdx.x & 7) * 144 + (blockIdx.x >> 3);
  int W = bs * 4 + (threadIdx.x >> 6);
  int b = W / 2304;
  int r = W % 2304;
  int i = r / 12;
  int j0 = (r % 12) * 16;
  int m = lane & 15, quad = lane >> 4;
  int j = j0 + m;
  const unsigned short* xpb = xp + (size_t)b * (194 * 194 * 32) + quad * 8;

  // ---- inline A: 3x3x32 conv; quad-lanes split channels, shfl-reduce.
  float a = 0.f;
  #pragma unroll
  for (int tap = 0; tap < 9; tap++) {
    int kh = tap / 3, kw = tap % 3;
    i32x4 v = *(const i32x4*)(xpb + ((i + kh) * 194 + (j + kw)) * 32);
    const f32x4* wp = (const f32x4*)(wlds + tap * 32 + quad * 8);
    f32x4 w0 = wp[0], w1 = wp[1];
    union { int ii; float ff; } u;
    u.ii = v[0] << 16;              a = fmaf(u.ff, w0[0], a);
    u.ii = v[0] & (int)0xffff0000u; a = fmaf(u.ff, w0[1], a);
    u.ii = v[1] << 16;              a = fmaf(u.ff, w0[2], a);
    u.ii = v[1] & (int)0xffff0000u; a = fmaf(u.ff, w0[3], a);
    u.ii = v[2] << 16;              a = fmaf(u.ff, w1[0], a);
    u.ii = v[2] & (int)0xffff0000u; a = fmaf(u.ff, w1[1], a);
    u.ii = v[3] << 16;              a = fmaf(u.ff, w1[2], a);
    u.ii = v[3] & (int)0xffff0000u; a = fmaf(u.ff, w1[3], a);
  }
  a += __shfl_xor(a, 16);
  a += __shfl_xor(a, 32);
  float A = a + p1b[0];

  // ---- sampling + MFMA
  f32x4 acc0 = {0.f, 0.f, 0.f, 0.f};
  f32x4 acc1 = acc0, acc2 = acc0, acc3 = acc0;
  float cx = (float)(i + 1), cy = (float)(j + 1);
  int icx = i + 1, icy = j + 1;

  #pragma unroll
  for (int n = 0; n < 9; n++) {
    const int dx = n / 3 - 1, dy = n % 3 - 1;
    f32x4 s0 = {0.f, 0.f, 0.f, 0.f}, s1 = s0;
    if (dx == 0 && dy == 0) {
      // exact center: g_lt == 1, others exactly 0
      i32x4 v = *(const i32x4*)(xpb + (icx * 194 + icy) * 32);
      add8(v, 1.0f, s0, s1);
    } else if (dy == 0) {
      // py == cy exactly: only lt,rb along x survive
      float px = cx + A * (float)dx;
      float flx = floorf(px);
      float qlx = fminf(fmaxf(flx, 0.f), 193.f);
      float qrx = fminf(fmaxf(flx + 1.f, 0.f), 193.f);
      float pxc = fminf(fmaxf(px, 0.f), 193.f);
      float gxl = 1.f + (qlx - pxc), gxr = 1.f - (qrx - pxc);
      i32x4 vl = *(const i32x4*)(xpb + ((int)qlx * 194 + icy) * 32);
      i32x4 vr = *(const i32x4*)(xpb + ((int)qrx * 194 + icy) * 32);
      add8(vl, gxl, s0, s1);
      add8(vr, gxr, s0, s1);
    } else if (dx == 0) {
      float py = cy + A * (float)dy;
      float fly = floorf(py);
      float qly = fminf(fmaxf(fly, 0.f), 193.f);
      float qry = fminf(fmaxf(fly + 1.f, 0.f), 193.f);
      float pyc = fminf(fmaxf(py, 0.f), 193.f);
      float gyl = 1.f + (qly - pyc), gyr = 1.f - (qry - pyc);
      i32x4 vl = *(const i32x4*)(xpb + (icx * 194 + (int)qly) * 32);
      i32x4 vr = *(const i32x4*)(xpb + (icx * 194 + (int)qry) * 32);
      add8(vl, gyl, s0, s1);
      add8(vr, gyr, s0, s1);
    } else {
      float px = cx + A * (float)dx;
      float py = cy + A * (float)dy;
      float flx = floorf(px), fly = floorf(py);
      float qlx = fminf(fmaxf(flx, 0.f), 193.f);
      float qly = fminf(fmaxf(fly, 0.f), 193.f);
      float qrx = fminf(fmaxf(flx + 1.f, 0.f), 193.f);
      float qry = fminf(fmaxf(fly + 1.f, 0.f), 193.f);
      float pxc = fminf(fmaxf(px, 0.f), 193.f);
      float pyc = fminf(fmaxf(py, 0.f), 193.f);
      float gxl = 1.f + (qlx - pxc), gxr = 1.f - (qrx - pxc);
      float gyl = 1.f + (qly - pyc), gyr = 1.f - (qry - pyc);
      int ixl = (int)qlx, iyl = (int)qly, ixr = (int)qrx, iyr = (int)qry;
      i32x4 vlt = *(const i32x4*)(xpb + (ixl * 194 + iyl) * 32);
      i32x4 vrb = *(const i32x4*)(xpb + (ixr * 194 + iyr) * 32);
      i32x4 vlb = *(const i32x4*)(xpb + (ixl * 194 + iyr) * 32);
      i32x4 vrt = *(const i32x4*)(xpb + (ixr * 194 + iyl) * 32);
      add8(vlt, gxl * gyl, s0, s1);
      add8(vrb, gxr * gyr, s0, s1);
      add8(vlb, gxl * gyr, s0, s1);
      add8(vrt, gxr * gyl, s0, s1);
    }
    s16x8 af;
    af[0] = (short)f2bf(s0[0]); af[1] = (short)f2bf(s0[1]);
    af[2] = (short)f2bf(s0[2]); af[3] = (short)f2bf(s0[3]);
    af[4] = (short)f2bf(s1[0]); af[5] = (short)f2bf(s1[1]);
    af[6] = (short)f2bf(s1[2]); af[7] = (short)f2bf(s1[3]);
    int wb = n * 256 + lane;
    acc0 = __builtin_amdgcn_mfma_f32_16x16x32_bf16(af, wfv[wb],       acc0, 0, 0, 0);
    acc1 = __builtin_amdgcn_mfma_f32_16x16x32_bf16(af, wfv[wb + 64],  acc1, 0, 0, 0);
    acc2 = __builtin_amdgcn_mfma_f32_16x16x32_bf16(af, wfv[wb + 128], acc2, 0, 0, 0);
    acc3 = __builtin_amdgcn_mfma_f32_16x16x32_bf16(af, wfv[wb + 192], acc3, 0, 0, 0);
  }

  // D layout: row(pixel) = quad*4 + reg, col(o) = lane&15
  int o0 = lane & 15;
  int jout = j0 + quad * 4;
  float* op = out + (size_t)b * 64 * 36864 + (size_t)o0 * 36864 + i * 192 + jout;
  *(f32x4*)(op) = acc0;
  *(f32x4*)(op + 16 * 36864) = acc1;
  *(f32x4*)(op + 32 * 36864) = acc2;
  *(f32x4*)(op + 48 * 36864) = acc3;
}

extern "C" void kernel_launch(void* const* d_in, const int* in_sizes, int n_in,
                              void* d_out, int out_size, void* d_ws, size_t ws_size,
                              hipStream_t stream) {
  const float* x      = (const float*)d_in[0];
  const float* conv_w = (const float*)d_in[1];
  const float* p1w    = (const float*)d_in[4];
  const float* p1b    = (const float*)d_in[5];
  float* out = (float*)d_out;

  unsigned short* xp = (unsigned short*)d_ws;        // 2*194*194*32 bf16
  short* wf = (short*)(xp + 2 * 194 * 194 * 32);     // 9*256*8 bf16

  k_prep<<<(2 * 194 * 194 * 4 + 255) / 256, 256, 0, stream>>>(x, xp);
  k_wfrag<<<9, 256, 0, stream>>>(conv_w, wf);
  k_main<<<1152, 256, 0, stream>>>(xp, p1w, p1b, (const s16x8*)wf, out);
}

// Round 4
// 97.831 us; speedup vs baseline: 1.6190x; 1.0259x over previous
//
#include <hip/hip_runtime.h>

typedef __attribute__((ext_vector_type(4))) float f32x4;
typedef __attribute__((ext_vector_type(4))) int   i32x4;
typedef __attribute__((ext_vector_type(8))) short s16x8;

__device__ __forceinline__ unsigned short f2bf_rn(float f) {
  union { float f; unsigned u; } v; v.f = f;
  unsigned r = v.u + 0x7fffu + ((v.u >> 16) & 1u);
  return (unsigned short)(r >> 16);
}

// pack two fp32 -> two bf16 (round-half-up) in one int via v_perm_b32
__device__ __forceinline__ int packbf2(float lo, float hi) {
  union { float f; unsigned u; } a, b; a.f = lo; b.f = hi;
  return (int)__builtin_amdgcn_perm(b.u + 0x8000u, a.u + 0x8000u, 0x07060302u);
}

// unpack 8 bf16 (i32x4) and accumulate g*x into s0(ch0..3), s1(ch4..7)
__device__ __forceinline__ void add8(i32x4 v, float g, f32x4& s0, f32x4& s1) {
  union { int ii; float ff; } u;
  u.ii = v[0] << 16;                  s0[0] = fmaf(g, u.ff, s0[0]);
  u.ii = v[0] & (int)0xffff0000u;     s0[1] = fmaf(g, u.ff, s0[1]);
  u.ii = v[1] << 16;                  s0[2] = fmaf(g, u.ff, s0[2]);
  u.ii = v[1] & (int)0xffff0000u;     s0[3] = fmaf(g, u.ff, s0[3]);
  u.ii = v[2] << 16;                  s1[0] = fmaf(g, u.ff, s1[0]);
  u.ii = v[2] & (int)0xffff0000u;     s1[1] = fmaf(g, u.ff, s1[1]);
  u.ii = v[3] << 16;                  s1[2] = fmaf(g, u.ff, s1[2]);
  u.ii = v[3] & (int)0xffff0000u;     s1[3] = fmaf(g, u.ff, s1[3]);
}

__device__ __forceinline__ void axis_cw(float p, int& il, int& ir, float& gl, float& gr) {
  float fl = floorf(p);
  float ql = fminf(fmaxf(fl, 0.f), 193.f);
  float qr = fminf(fmaxf(fl + 1.f, 0.f), 193.f);
  float pc = fminf(fmaxf(p, 0.f), 193.f);
  gl = 1.f + (ql - pc);
  gr = 1.f - (qr - pc);
  il = (int)ql; ir = (int)qr;
}

// K0 merged: blocks [0,1177): NCHW fp32 -> zero-padded bf16 NHWC xp (2,194,194,32)
//            blocks tail:      conv_w -> bf16 MFMA B-fragments
__global__ __launch_bounds__(256) void k_prep(const float* __restrict__ x,
                                              unsigned short* __restrict__ xp,
                                              const float* __restrict__ w,
                                              short* __restrict__ wf) {
  int t = blockIdx.x * 256 + threadIdx.x;
  if (t < 2 * 194 * 194 * 4) {
    int pix = t >> 2, c8 = t & 3;
    int b = pix / (194 * 194);
    int r = pix % (194 * 194);
    int i = r / 194 - 1, j = r % 194 - 1;
    bool ok = ((unsigned)i < 192u) && ((unsigned)j < 192u);
    const float* src = x + (size_t)b * 32 * 36864 + (size_t)(c8 * 8) * 36864 + i * 192 + j;
    unsigned v[8];
    #pragma unroll
    for (int k = 0; k < 8; k++) v[k] = ok ? (unsigned)f2bf_rn(src[k * 36864]) : 0u;
    i32x4 pv;
    pv[0] = (int)(v[0] | (v[1] << 16));
    pv[1] = (int)(v[2] | (v[3] << 16));
    pv[2] = (int)(v[4] | (v[5] << 16));
    pv[3] = (int)(v[6] | (v[7] << 16));
    *(i32x4*)(xp + (size_t)pix * 32 + c8 * 8) = pv;
  } else {
    int u = t - 2 * 194 * 194 * 4;
    if (u >= 9 * 4 * 64) return;
    int n = u / 256;
    int ot = (u / 64) % 4;
    int lane = u % 64;
    int o = ot * 16 + (lane & 15);
    int cb = (lane >> 4) * 8;
    #pragma unroll
    for (int jj = 0; jj < 8; jj++) {
      float v = w[(o * 32 + cb + jj) * 9 + n];
      wf[(size_t)u * 8 + jj] = (short)f2bf_rn(v);
    }
  }
}

// K1: fused A-map + pipelined bilinear sampling + MFMA contraction.
__global__ __launch_bounds__(256) void k_main(const unsigned short* __restrict__ xp,
                                              const float* __restrict__ p1w,
                                              const float* __restrict__ p1b,
                                              const s16x8* __restrict__ wfv,
                                              float* __restrict__ out) {
  __shared__ float wlds[288];  // reordered p1w: wlds[tap*32 + c]
  for (int idx = threadIdx.x; idx < 288; idx += 256) {
    int c = idx / 9, tap = idx % 9;
    wlds[tap * 32 + c] = p1w[idx];
  }
  __syncthreads();

  int lane = threadIdx.x & 63;
  // XCD swizzle: 1152 blocks = 8 XCDs x 144 contiguous row-segments.
  int bs = (blockIdx.x & 7) * 144 + (blockIdx.x >> 3);
  int W = bs * 4 + (threadIdx.x >> 6);
  int b = W / 2304;
  int r = W % 2304;
  int i = r / 12;
  int j0 = (r % 12) * 16;
  int m = lane & 15, quad = lane >> 4;
  int j = j0 + m;
  const unsigned short* xpb = xp + (size_t)b * (194 * 194 * 32) + quad * 8;

  // ---- inline A: 3x3x32 conv; quads split channels, shfl-reduce; keep center tap.
  float a = 0.f;
  i32x4 vcen;
  #pragma unroll
  for (int tap = 0; tap < 9; tap++) {
    int kh = tap / 3, kw = tap % 3;
    i32x4 v = *(const i32x4*)(xpb + ((i + kh) * 194 + (j + kw)) * 32);
    if (tap == 4) vcen = v;
    const f32x4* wp = (const f32x4*)(wlds + tap * 32 + quad * 8);
    f32x4 w0 = wp[0], w1 = wp[1];
    union { int ii; float ff; } u;
    u.ii = v[0] << 16;              a = fmaf(u.ff, w0[0], a);
    u.ii = v[0] & (int)0xffff0000u; a = fmaf(u.ff, w0[1], a);
    u.ii = v[1] << 16;              a = fmaf(u.ff, w0[2], a);
    u.ii = v[1] & (int)0xffff0000u; a = fmaf(u.ff, w0[3], a);
    u.ii = v[2] << 16;              a = fmaf(u.ff, w1[0], a);
    u.ii = v[2] & (int)0xffff0000u; a = fmaf(u.ff, w1[1], a);
    u.ii = v[3] << 16;              a = fmaf(u.ff, w1[2], a);
    u.ii = v[3] & (int)0xffff0000u; a = fmaf(u.ff, w1[3], a);
  }
  a += __shfl_xor(a, 16);
  a += __shfl_xor(a, 32);
  float A = a + p1b[0];

  // ---- all offsets & weights up front (steps n != 4)
  float cx = (float)(i + 1), cy = (float)(j + 1);
  int icx = i + 1, icy = j + 1;
  int offs[9][4];
  float gws[9][4];
  #pragma unroll
  for (int n = 0; n < 9; n++) {
    const int dx = n / 3 - 1, dy = n % 3 - 1;
    if (dx == 0 && dy == 0) continue;
    if (dy == 0) {
      int il, ir; float gl, gr;
      axis_cw(cx + A * (float)dx, il, ir, gl, gr);
      offs[n][0] = (il * 194 + icy) * 32; gws[n][0] = gl;
      offs[n][1] = (ir * 194 + icy) * 32; gws[n][1] = gr;
    } else if (dx == 0) {
      int il, ir; float gl, gr;
      axis_cw(cy + A * (float)dy, il, ir, gl, gr);
      offs[n][0] = (icx * 194 + il) * 32; gws[n][0] = gl;
      offs[n][1] = (icx * 194 + ir) * 32; gws[n][1] = gr;
    } else {
      int ilx, irx, ily, iry; float gxl, gxr, gyl, gyr;
      axis_cw(cx + A * (float)dx, ilx, irx, gxl, gxr);
      axis_cw(cy + A * (float)dy, ily, iry, gyl, gyr);
      offs[n][0] = (ilx * 194 + ily) * 32; gws[n][0] = gxl * gyl;
      offs[n][1] = (irx * 194 + iry) * 32; gws[n][1] = gxr * gyr;
      offs[n][2] = (ilx * 194 + iry) * 32; gws[n][2] = gxl * gyr;
      offs[n][3] = (irx * 194 + ily) * 32; gws[n][3] = gxr * gyl;
    }
  }

  const int cnt[9] = {4, 2, 4, 2, 0, 2, 4, 2, 4};
  i32x4 dat[9][4];
  f32x4 acc0 = {0.f, 0.f, 0.f, 0.f};
  f32x4 acc1 = acc0, acc2 = acc0, acc3 = acc0;

#define LOAD_STEP(n)                                                      \
  { _Pragma("unroll") for (int c = 0; c < 4; c++)                         \
      if (c < cnt[n]) dat[n][c] = *(const i32x4*)(xpb + offs[n][c]); }

#define PROC_STEP(n)                                                      \
  { f32x4 s0 = {0.f, 0.f, 0.f, 0.f}, s1 = s0;                             \
    _Pragma("unroll") for (int c = 0; c < 4; c++)                         \
      if (c < cnt[n]) add8(dat[n][c], gws[n][c], s0, s1);                 \
    s16x8 af; int* ai = (int*)&af;                                        \
    ai[0] = packbf2(s0[0], s0[1]); ai[1] = packbf2(s0[2], s0[3]);         \
    ai[2] = packbf2(s1[0], s1[1]); ai[3] = packbf2(s1[2], s1[3]);         \
    int wb = (n) * 256 + lane;                                            \
    acc0 = __builtin_amdgcn_mfma_f32_16x16x32_bf16(af, wfv[wb],       acc0, 0, 0, 0); \
    acc1 = __builtin_amdgcn_mfma_f32_16x16x32_bf16(af, wfv[wb + 64],  acc1, 0, 0, 0); \
    acc2 = __builtin_amdgcn_mfma_f32_16x16x32_bf16(af, wfv[wb + 128], acc2, 0, 0, 0); \
    acc3 = __builtin_amdgcn_mfma_f32_16x16x32_bf16(af, wfv[wb + 192], acc3, 0, 0, 0); }

  // pipeline: group0 {0,1,2}, group1 {3,5}, group2 {6,7,8}; center free.
  LOAD_STEP(0) LOAD_STEP(1) LOAD_STEP(2)
  LOAD_STEP(3) LOAD_STEP(5)
  PROC_STEP(0) PROC_STEP(1) PROC_STEP(2)
  LOAD_STEP(6) LOAD_STEP(7) LOAD_STEP(8)
  {  // center step n=4: xp is bf16 — fragment is a pure bitcast of vcen
    s16x8 af; int* ai = (int*)&af;
    ai[0] = vcen[0]; ai[1] = vcen[1]; ai[2] = vcen[2]; ai[3] = vcen[3];
    int wb = 4 * 256 + lane;
    acc0 = __builtin_amdgcn_mfma_f32_16x16x32_bf16(af, wfv[wb],       acc0, 0, 0, 0);
    acc1 = __builtin_amdgcn_mfma_f32_16x16x32_bf16(af, wfv[wb + 64],  acc1, 0, 0, 0);
    acc2 = __builtin_amdgcn_mfma_f32_16x16x32_bf16(af, wfv[wb + 128], acc2, 0, 0, 0);
    acc3 = __builtin_amdgcn_mfma_f32_16x16x32_bf16(af, wfv[wb + 192], acc3, 0, 0, 0);
  }
  PROC_STEP(3) PROC_STEP(5)
  PROC_STEP(6) PROC_STEP(7) PROC_STEP(8)
#undef LOAD_STEP
#undef PROC_STEP

  // D layout: row(pixel) = quad*4 + reg, col(o) = lane&15
  int o0 = lane & 15;
  int jout = j0 + quad * 4;
  float* op = out + (size_t)b * 64 * 36864 + (size_t)o0 * 36864 + i * 192 + jout;
  *(f32x4*)(op) = acc0;
  *(f32x4*)(op + 16 * 36864) = acc1;
  *(f32x4*)(op + 32 * 36864) = acc2;
  *(f32x4*)(op + 48 * 36864) = acc3;
}

extern "C" void kernel_launch(void* const* d_in, const int* in_sizes, int n_in,
                              void* d_out, int out_size, void* d_ws, size_t ws_size,
                              hipStream_t stream) {
  const float* x      = (const float*)d_in[0];
  const float* conv_w = (const float*)d_in[1];
  const float* p1w    = (const float*)d_in[4];
  const float* p1b    = (const float*)d_in[5];
  float* out = (float*)d_out;

  unsigned short* xp = (unsigned short*)d_ws;     // 2*194*194*32 bf16
  short* wf = (short*)(xp + 2 * 194 * 194 * 32);  // 9*256*8 bf16

  int prep_threads = 2 * 194 * 194 * 4 + 9 * 4 * 64;
  k_prep<<<(prep_threads + 255) / 256, 256, 0, stream>>>(x, xp, conv_w, wf);
  k_main<<<1152, 256, 0, stream>>>(xp, p1w, p1b, (const s16x8*)wf, out);
}